// Round 9
// baseline (1850.056 us; speedup 1.0000x reference)
//
#include <hip/hip_runtime.h>
#include <cstdint>
#include <cstddef>
#include <cmath>

// ---------------------------------------------------------------------------
// Round 10b (resubmit x3; R6/R7/R8 benches never acquired a GPU):
// 4-phase interleaved GEMM schedule (T3+T4+T5 port), race-fixed.
// vs R10: barrier #4 between phase-3's frag reads/MFMAs and wave-3's stageA.
// Per K-tile (dbuf, 5 barriers/iter):
//   ph0: ds_read B[0..3]+A[0]; prio1; 12 MFMA; prio0; bar
//   ph1: ds_read A[1]; stage B(ki+2, all waves)+A(wave0); MFMA; bar
//   ph2: ds_read A[2]; stage A(wave1); MFMA; bar
//   ph3: ds_read A[3]; stage A(wave2); MFMA; bar
//   tail: stage A(wave3); vmcnt(8); bar
// Chunk discipline: A-chunk{w,4+w} staged by wave w, read in phase w.
// SPLITA (layer-0 G1) keeps the R6 single-buffer path.
// ---------------------------------------------------------------------------

#define EPS_BN 1e-5f

typedef unsigned short u16;
typedef short short8 __attribute__((ext_vector_type(8)));
typedef u16 u16x8 __attribute__((ext_vector_type(8)));
typedef u16 u16x4 __attribute__((ext_vector_type(4)));
typedef float fx4 __attribute__((ext_vector_type(4)));

__device__ __forceinline__ u16 bf16_rn(float f) {
  unsigned u = __float_as_uint(f);
  return (u16)((u + 0x7FFFu + ((u >> 16) & 1u)) >> 16);
}
__device__ __forceinline__ float bf16_f(u16 h) {
  return __uint_as_float(((unsigned)h) << 16);
}

// async global->LDS, 16B per lane; LDS dest = wave-uniform base + lane*16
__device__ __forceinline__ void gload16(const void* g, void* l) {
  __builtin_amdgcn_global_load_lds(
      (const __attribute__((address_space(1))) void*)g,
      (__attribute__((address_space(3))) void*)l, 16, 0, 0);
}

#define MEMFENCE() asm volatile("" ::: "memory")

// ---- XCD-ownership swizzle: bijection blockIdx -> (mt, nt) ----------------
__device__ __forceinline__ void map_tile(int b, int tm, int tn, int T,
                                         int& mt, int& nt) {
  const int x = b & 7;
  const int s = b >> 3;
  const int cap = ((tm - x + 7) >> 3) * tn;  // slots in x's owned region
  if (s < cap) {
    const int q = s / tn;
    mt = x + (q << 3);
    nt = s - q * tn;
    return;
  }
  int r = s - cap;  // overflow rank (within this XCD's overflow)
  for (int xp = 0; xp < x; ++xp) {
    const int nbp = (T - xp + 7) >> 3;
    const int capp = ((tm - xp + 7) >> 3) * tn;
    if (nbp > capp) r += nbp - capp;
  }
  for (int xq = 0; xq < 8; ++xq) {
    const int nbq = (T - xq + 7) >> 3;
    const int capq = ((tm - xq + 7) >> 3) * tn;
    const int def = capq - nbq;
    if (def > 0) {
      if (r < def) {
        const int sq = nbq + r;
        const int q = sq / tn;
        mt = xq + (q << 3);
        nt = sq - q * tn;
        return;
      }
      r -= def;
    }
  }
  mt = 0; nt = 0;  // unreachable
}

// ================= 4-phase GEMM (split-bf16 A and B inputs) ================
// C(MxN) = act(A @ B + bias). Ahi/Alo: M x K bf16 (lda, K-pads = 0).
// Bhi/Blo: N x K bf16 (ldb, K-pads = 0). OUTMODE 0: fp32 C (zero pad cols);
// OUTMODE 1: bias+relu -> split bf16. Block 128x128, BK=32, 4 waves (2x2).
template <int OUTMODE>
__global__ __launch_bounds__(256, 2) void gemm_ph(
    const u16* __restrict__ Ahi, const u16* __restrict__ Alo,
    const u16* __restrict__ Bhi, const u16* __restrict__ Blo,
    const float* __restrict__ bias,
    float* __restrict__ Cf, u16* __restrict__ Chi, u16* __restrict__ Clo,
    int M, int N, int K, int lda, int ldb, int ldc, int tm, int tn) {
  __shared__ __align__(16) u16 As[2][2][128 * 32];  // [buf][hi/lo]
  __shared__ __align__(16) u16 Bs[2][2][128 * 32];

  int mt, nt;
  map_tile(blockIdx.x, tm, tn, tm * tn, mt, nt);
  const int m0 = mt * 128;
  const int n0 = nt * 128;

  const int tid = threadIdx.x;
  const int lane = tid & 63;
  const int wid = tid >> 6;
  const int wm = (wid >> 1) * 64;
  const int wn = (wid & 1) * 64;
  const int quad = lane >> 4;
  const int l15 = lane & 15;

  // staging: thread -> (row = tid>>2, 16B slot = tid&3), slot hash f(row)
  const int srow = tid >> 2;
  const int sg = ((tid & 3) ^ srow ^ (srow >> 2)) & 3;
  int ar0 = m0 + srow;      if (ar0 >= M) ar0 = M - 1;
  int ar1 = m0 + srow + 64; if (ar1 >= M) ar1 = M - 1;
  int br0 = n0 + srow;      if (br0 >= N) br0 = N - 1;
  int br1 = n0 + srow + 64; if (br1 >= N) br1 = N - 1;
  const size_t aof0 = (size_t)ar0 * lda + (sg << 3);
  const size_t aof1 = (size_t)ar1 * lda + (sg << 3);
  const size_t bof0 = (size_t)br0 * ldb + (sg << 3);
  const size_t bof1 = (size_t)br1 * ldb + (sg << 3);
  const int l0 = wid << 9;           // wave stages chunk wid (rows 16w..16w+15)
  const int l1 = 2048 + (wid << 9);  // and chunk 4+wid (rows 64+16w..)

  fx4 zf = {0.f, 0.f, 0.f, 0.f};
  fx4 acc[4][4];
#pragma unroll
  for (int a = 0; a < 4; ++a)
#pragma unroll
    for (int b = 0; b < 4; ++b) acc[a][b] = zf;

  const int nk = (K + 31) >> 5;

  auto stageA = [&](int kt, int bufi) {
    const size_t kk = (size_t)kt << 5;
    gload16(Ahi + aof0 + kk, &As[bufi][0][l0]);
    gload16(Ahi + aof1 + kk, &As[bufi][0][l1]);
    gload16(Alo + aof0 + kk, &As[bufi][1][l0]);
    gload16(Alo + aof1 + kk, &As[bufi][1][l1]);
  };
  auto stageB = [&](int kt, int bufi) {
    const size_t kk = (size_t)kt << 5;
    gload16(Bhi + bof0 + kk, &Bs[bufi][0][l0]);
    gload16(Bhi + bof1 + kk, &Bs[bufi][0][l1]);
    gload16(Blo + bof0 + kk, &Bs[bufi][1][l0]);
    gload16(Blo + bof1 + kk, &Bs[bufi][1][l1]);
  };

  // ---- prologue: stage tiles 0 and 1; wait tile 0 ----
  stageA(0, 0); stageB(0, 0);
  if (nk > 1) { stageA(1, 1); stageB(1, 1); }
  if (nk > 1) asm volatile("s_waitcnt vmcnt(8)" ::: "memory");
  else        asm volatile("s_waitcnt vmcnt(0)" ::: "memory");
  __builtin_amdgcn_s_barrier();
  MEMFENCE();

  for (int ki = 0; ki < nk; ++ki) {
    const int cur = ki & 1;
    const bool st = (ki + 2) < nk;

    short8 bh[4], bl[4], ah, al;
    // ---- phase 0: all B frags + A chunk 0; MFMA a=0 ----
#pragma unroll
    for (int t = 0; t < 4; ++t) {
      const int rB = wn + t * 16 + l15;
      const int ob = rB * 32 + (((quad ^ rB ^ (rB >> 2)) & 3) << 3);
      bh[t] = *(const short8*)&Bs[cur][0][ob];
      bl[t] = *(const short8*)&Bs[cur][1][ob];
    }
    {
      const int rA = wm + l15;
      const int oa = rA * 32 + (((quad ^ rA ^ (rA >> 2)) & 3) << 3);
      ah = *(const short8*)&As[cur][0][oa];
      al = *(const short8*)&As[cur][1][oa];
    }
    __builtin_amdgcn_s_setprio(1);
#pragma unroll
    for (int b = 0; b < 4; ++b) {
      acc[0][b] = __builtin_amdgcn_mfma_f32_16x16x32_bf16(ah, bh[b], acc[0][b], 0, 0, 0);
      acc[0][b] = __builtin_amdgcn_mfma_f32_16x16x32_bf16(ah, bl[b], acc[0][b], 0, 0, 0);
      acc[0][b] = __builtin_amdgcn_mfma_f32_16x16x32_bf16(al, bh[b], acc[0][b], 0, 0, 0);
    }
    __builtin_amdgcn_s_setprio(0);
    MEMFENCE();
    __builtin_amdgcn_s_barrier();
    MEMFENCE();

    // ---- phases 1..3: A chunk t; staged prefetch slices; MFMA a=t ----
#pragma unroll
    for (int t = 1; t < 4; ++t) {
      const int rA = wm + t * 16 + l15;
      const int oa = rA * 32 + (((quad ^ rA ^ (rA >> 2)) & 3) << 3);
      ah = *(const short8*)&As[cur][0][oa];
      al = *(const short8*)&As[cur][1][oa];
      if (t == 1 && st) {
        stageB(ki + 2, cur);                // B chunks freed after ph0's bar
        if (wid == 0) stageA(ki + 2, cur);  // chunks {0,4} freed after ph0
      }
      if (t == 2 && st && wid == 1) stageA(ki + 2, cur);  // {1,5} after ph1
      if (t == 3 && st && wid == 2) stageA(ki + 2, cur);  // {2,6} after ph2
      __builtin_amdgcn_s_setprio(1);
#pragma unroll
      for (int b = 0; b < 4; ++b) {
        acc[t][b] = __builtin_amdgcn_mfma_f32_16x16x32_bf16(ah, bh[b], acc[t][b], 0, 0, 0);
        acc[t][b] = __builtin_amdgcn_mfma_f32_16x16x32_bf16(ah, bl[b], acc[t][b], 0, 0, 0);
        acc[t][b] = __builtin_amdgcn_mfma_f32_16x16x32_bf16(al, bh[b], acc[t][b], 0, 0, 0);
      }
      __builtin_amdgcn_s_setprio(0);
      MEMFENCE();
      __builtin_amdgcn_s_barrier();   // after t==3 this is barrier #4:
      MEMFENCE();                     // all ph3 reads of chunks {3,7} retired
    }
    // race-fix: wave 3 stages chunks {3,7} only after barrier #4
    if (st && wid == 3) stageA(ki + 2, cur);
    // counted drain: tile ki+1 landed; tile ki+2 (8 loads/wave) in flight
    if (st)                asm volatile("s_waitcnt vmcnt(8)" ::: "memory");
    else if (ki + 1 < nk)  asm volatile("s_waitcnt vmcnt(0)" ::: "memory");
    MEMFENCE();
    __builtin_amdgcn_s_barrier();
    MEMFENCE();
  }

#pragma unroll
  for (int a = 0; a < 4; ++a)
#pragma unroll
    for (int b = 0; b < 4; ++b) {
      const int gn = n0 + wn + b * 16 + l15;
      if (gn >= ldc) continue;
      const bool live = gn < N;
      const float bv = (OUTMODE == 1 && live) ? bias[gn] : 0.f;
#pragma unroll
      for (int r = 0; r < 4; ++r) {
        const int gm = m0 + wm + a * 16 + quad * 4 + r;
        if (gm >= M) continue;
        float v = live ? acc[a][b][r] : 0.f;
        if (OUTMODE == 1) {
          v = live ? fmaxf(v + bv, 0.f) : 0.f;
          const u16 hb = bf16_rn(v);
          Chi[(size_t)gm * ldc + gn] = hb;
          Clo[(size_t)gm * ldc + gn] = bf16_rn(v - bf16_f(hb));
        } else {
          Cf[(size_t)gm * ldc + gn] = v;
        }
      }
    }
}

// ================= R6-path GEMM for fp32-A (layer-0 G1 only) ===============
__global__ __launch_bounds__(256, 2) void gemm_splita(
    const float* __restrict__ Af,
    const u16* __restrict__ Bhi, const u16* __restrict__ Blo,
    const float* __restrict__ bias,
    u16* __restrict__ Chi, u16* __restrict__ Clo,
    int M, int N, int K, int lda, int ldb, int ldc, int tm, int tn) {
  __shared__ __align__(16) u16 As[2][128 * 32];
  __shared__ __align__(16) u16 Bs[2][128 * 32];

  int mt, nt;
  map_tile(blockIdx.x, tm, tn, tm * tn, mt, nt);
  const int m0 = mt * 128;
  const int n0 = nt * 128;

  const int tid = threadIdx.x;
  const int lane = tid & 63;
  const int wid = tid >> 6;
  const int wm = (wid >> 1) * 64;
  const int wn = (wid & 1) * 64;
  const int quad = lane >> 4;
  const int l15 = lane & 15;

  const int srow = tid >> 2;
  const int sg = ((tid & 3) ^ srow ^ (srow >> 2)) & 3;
  int ar0 = m0 + srow;      if (ar0 >= M) ar0 = M - 1;
  int ar1 = m0 + srow + 64; if (ar1 >= M) ar1 = M - 1;
  int br0 = n0 + srow;      if (br0 >= N) br0 = N - 1;
  int br1 = n0 + srow + 64; if (br1 >= N) br1 = N - 1;
  const size_t aof0 = (size_t)ar0 * lda + (sg << 3);
  const size_t aof1 = (size_t)ar1 * lda + (sg << 3);
  const size_t bof0 = (size_t)br0 * ldb + (sg << 3);
  const size_t bof1 = (size_t)br1 * ldb + (sg << 3);
  const int l0 = wid << 9;
  const int l1 = 2048 + (wid << 9);
  const int wls = srow * 32 + ((tid & 3) << 3);

  fx4 zf = {0.f, 0.f, 0.f, 0.f};
  fx4 acc[4][4];
#pragma unroll
  for (int a = 0; a < 4; ++a)
#pragma unroll
    for (int b = 0; b < 4; ++b) acc[a][b] = zf;

  const int nk = (K + 31) >> 5;
  for (int ki = 0; ki < nk; ++ki) {
    const int k0 = ki << 5;
    u16x8 va_h[2], va_l[2];
#pragma unroll
    for (int it = 0; it < 2; ++it) {
      const float* pp = Af + (it ? aof1 : aof0) + k0;
      const fx4 f0 = *(const fx4*)pp;
      const fx4 f1 = *(const fx4*)(pp + 4);
      u16x8 h, l;
#pragma unroll
      for (int j = 0; j < 4; ++j) {
        const u16 hb = bf16_rn(f0[j]);
        h[j] = hb;
        l[j] = bf16_rn(f0[j] - bf16_f(hb));
      }
#pragma unroll
      for (int j = 0; j < 4; ++j) {
        const u16 hb = bf16_rn(f1[j]);
        h[4 + j] = hb;
        l[4 + j] = bf16_rn(f1[j] - bf16_f(hb));
      }
      va_h[it] = h;
      va_l[it] = l;
    }

    if (ki) __syncthreads();

    gload16(Bhi + bof0 + k0, &Bs[0][l0]);
    gload16(Bhi + bof1 + k0, &Bs[0][l1]);
    gload16(Blo + bof0 + k0, &Bs[1][l0]);
    gload16(Blo + bof1 + k0, &Bs[1][l1]);
    *(u16x8*)&As[0][wls] = va_h[0];
    *(u16x8*)&As[0][wls + 2048] = va_h[1];
    *(u16x8*)&As[1][wls] = va_l[0];
    *(u16x8*)&As[1][wls + 2048] = va_l[1];
    __syncthreads();

    short8 ah[4], al[4], bh[4], bl[4];
#pragma unroll
    for (int t = 0; t < 4; ++t) {
      const int rA = wm + t * 16 + l15;
      const int oa = rA * 32 + (((quad ^ rA ^ (rA >> 2)) & 3) << 3);
      ah[t] = *(const short8*)&As[0][oa];
      al[t] = *(const short8*)&As[1][oa];
      const int rB = wn + t * 16 + l15;
      const int ob = rB * 32 + (((quad ^ rB ^ (rB >> 2)) & 3) << 3);
      bh[t] = *(const short8*)&Bs[0][ob];
      bl[t] = *(const short8*)&Bs[1][ob];
    }
#pragma unroll
    for (int a = 0; a < 4; ++a)
#pragma unroll
      for (int b = 0; b < 4; ++b) {
        acc[a][b] = __builtin_amdgcn_mfma_f32_16x16x32_bf16(ah[a], bh[b], acc[a][b], 0, 0, 0);
        acc[a][b] = __builtin_amdgcn_mfma_f32_16x16x32_bf16(ah[a], bl[b], acc[a][b], 0, 0, 0);
        acc[a][b] = __builtin_amdgcn_mfma_f32_16x16x32_bf16(al[a], bh[b], acc[a][b], 0, 0, 0);
      }
  }

#pragma unroll
  for (int a = 0; a < 4; ++a)
#pragma unroll
    for (int b = 0; b < 4; ++b) {
      const int gn = n0 + wn + b * 16 + l15;
      if (gn >= ldc) continue;
      const bool live = gn < N;
      const float bv = live ? bias[gn] : 0.f;
#pragma unroll
      for (int r = 0; r < 4; ++r) {
        const int gm = m0 + wm + a * 16 + quad * 4 + r;
        if (gm < M) {
          float v = live ? fmaxf(acc[a][b][r] + bv, 0.f) : 0.f;
          const u16 hb = bf16_rn(v);
          Chi[(size_t)gm * ldc + gn] = hb;
          Clo[(size_t)gm * ldc + gn] = bf16_rn(v - bf16_f(hb));
        }
      }
    }
}

// ================= weight prep: transpose + split (batched) ================
struct TSJob { const float* W; u16* Th; u16* Tl; int K; int Kp; int N; int tiles_k; int base; };
struct TSJobs { TSJob j[12]; };

__global__ __launch_bounds__(256) void transpose_split_all(TSJobs jobs, int njobs) {
  const int b = blockIdx.x;
  int ji = 0;
  while (ji + 1 < njobs && jobs.j[ji + 1].base <= b) ++ji;
  const TSJob J = jobs.j[ji];
  const int t = b - J.base;
  const int k0 = (t % J.tiles_k) * 32;
  const int n0 = (t / J.tiles_k) * 32;
  __shared__ float tile[32][33];
  const int tx = threadIdx.x & 31, ty = threadIdx.x >> 5;
#pragma unroll
  for (int i = 0; i < 32; i += 8) {
    const int k = k0 + ty + i, n = n0 + tx;
    tile[ty + i][tx] = (k < J.K && n < J.N) ? J.W[(size_t)k * J.N + n] : 0.f;
  }
  __syncthreads();
#pragma unroll
  for (int i = 0; i < 32; i += 8) {
    const int n = n0 + ty + i, k = k0 + tx;
    if (n < J.N && k < J.Kp) {
      const float f = tile[tx][ty + i];
      const u16 hb = bf16_rn(f);
      J.Th[(size_t)n * J.Kp + k] = hb;
      J.Tl[(size_t)n * J.Kp + k] = bf16_rn(f - bf16_f(hb));
    }
  }
}

// ========================= Graph preprocessing =============================
__global__ void count_deg(const int* __restrict__ dst, int E, int* __restrict__ cnt) {
  int e = blockIdx.x * blockDim.x + threadIdx.x;
  if (e < E) atomicAdd(&cnt[dst[e]], 1);
}

__global__ void compute_dinv(const int* __restrict__ cnt, float* __restrict__ dinv, int N) {
  int i = blockIdx.x * blockDim.x + threadIdx.x;
  if (i < N) dinv[i] = rsqrtf((float)(cnt[i] + 1));
}

__global__ void scan_block(const int* __restrict__ cnt, int* __restrict__ partial,
                           int* __restrict__ blocksum, int N) {
  __shared__ int s[256];
  const int t = threadIdx.x;
  const int i = blockIdx.x * 256 + t;
  int v = (i < N) ? cnt[i] : 0;
  s[t] = v;
  __syncthreads();
  for (int off = 1; off < 256; off <<= 1) {
    int u = (t >= off) ? s[t - off] : 0;
    __syncthreads();
    s[t] += u;
    __syncthreads();
  }
  if (i < N) partial[i] = s[t];
  if (t == 255) blocksum[blockIdx.x] = s[255];
}

__global__ void scan_sums(int* __restrict__ blocksum, int NB) {
  __shared__ int s[256];
  const int t = threadIdx.x;
  int v = (t < NB) ? blocksum[t] : 0;
  s[t] = v;
  __syncthreads();
  for (int off = 1; off < 256; off <<= 1) {
    int u = (t >= off) ? s[t - off] : 0;
    __syncthreads();
    s[t] += u;
    __syncthreads();
  }
  if (t < NB) blocksum[t] = s[t] - v;
}

__global__ void finalize_rowptr(const int* __restrict__ partial, const int* __restrict__ blockoff,
                                int* __restrict__ rowptr, int N) {
  int i = blockIdx.x * 256 + threadIdx.x;
  if (i < N) rowptr[i + 1] = partial[i] + blockoff[blockIdx.x];
  if (i == 0) rowptr[0] = 0;
}

__global__ void fill_csr(const int* __restrict__ src, const int* __restrict__ dst, int E,
                         const int* __restrict__ rowptr, int* __restrict__ cursor,
                         int* __restrict__ colidx) {
  int e = blockIdx.x * blockDim.x + threadIdx.x;
  if (e < E) {
    int d = dst[e];
    int p = atomicAdd(&cursor[d], 1);
    colidx[rowptr[d] + p] = src[e];
  }
}

// ================= Message passing + bias + BN + ReLU ======================
__global__ void mp_bn_relu(
    const float* __restrict__ H, const int* __restrict__ rowptr,
    const int* __restrict__ colidx, const float* __restrict__ dinv,
    const float* __restrict__ gb, const float* __restrict__ gamma,
    const float* __restrict__ beta, const float* __restrict__ mean,
    const float* __restrict__ var,
    u16* __restrict__ Xh, u16* __restrict__ Xl, int N, int F, int Fp) {
  const int nch = Fp >> 2;
  const int idx = blockIdx.x * blockDim.x + threadIdx.x;
  if (idx >= N * nch) return;
  const int i = idx / nch;
  const int c = idx - i * nch;
  const size_t rowi = (size_t)i * Fp + (c << 2);
  if ((c << 2) >= F) {
    const u16x4 z = {0, 0, 0, 0};
    *(u16x4*)(Xh + rowi) = z;
    *(u16x4*)(Xl + rowi) = z;
    return;
  }
  const float di = dinv[i];
  fx4 acc = (di * di) * *(const fx4*)(H + rowi);
  const int e0 = rowptr[i], e1 = rowptr[i + 1];
  int e = e0;
  for (; e + 4 <= e1; e += 4) {
    const int s0 = colidx[e + 0], s1 = colidx[e + 1];
    const int s2 = colidx[e + 2], s3 = colidx[e + 3];
    const float w0 = di * dinv[s0], w1 = di * dinv[s1];
    const float w2 = di * dinv[s2], w3 = di * dinv[s3];
    const fx4 v0 = *(const fx4*)(H + (size_t)s0 * Fp + (c << 2));
    const fx4 v1 = *(const fx4*)(H + (size_t)s1 * Fp + (c << 2));
    const fx4 v2 = *(const fx4*)(H + (size_t)s2 * Fp + (c << 2));
    const fx4 v3 = *(const fx4*)(H + (size_t)s3 * Fp + (c << 2));
    acc += w0 * v0;
    acc += w1 * v1;
    acc += w2 * v2;
    acc += w3 * v3;
  }
  for (; e < e1; ++e) {
    const int s = colidx[e];
    acc += (di * dinv[s]) * *(const fx4*)(H + (size_t)s * Fp + (c << 2));
  }
  u16x4 oh, ol;
#pragma unroll
  for (int j = 0; j < 4; ++j) {
    const int col = (c << 2) + j;
    float v = (acc[j] + gb[col] - mean[col]) * rsqrtf(var[col] + EPS_BN) * gamma[col] + beta[col];
    v = fmaxf(v, 0.f);
    const u16 hb = bf16_rn(v);
    oh[j] = hb;
    ol[j] = bf16_rn(v - bf16_f(hb));
  }
  *(u16x4*)(Xh + rowi) = oh;
  *(u16x4*)(Xl + rowi) = ol;
}

// ========================= global max pool (segments) ======================
__global__ void pool_seg(const u16* __restrict__ Xh, const u16* __restrict__ Xl,
                         const int* __restrict__ batch, float* __restrict__ out,
                         int N, int F, int ldx) {
  const int g = blockIdx.x;
  int lo = 0, hi = N;
  while (lo < hi) { int m = (lo + hi) >> 1; if (batch[m] < g) lo = m + 1; else hi = m; }
  const int s0 = lo;
  hi = N;
  while (lo < hi) { int m = (lo + hi) >> 1; if (batch[m] <= g) lo = m + 1; else hi = m; }
  const int s1 = lo;
  const int c = threadIdx.x;
  if (c * 4 >= F) return;
  fx4 mx = {-INFINITY, -INFINITY, -INFINITY, -INFINITY};
  for (int i = s0; i < s1; ++i) {
    const size_t off = (size_t)i * ldx + (c << 2);
    const u16x4 h = *(const u16x4*)(Xh + off);
    const u16x4 l = *(const u16x4*)(Xl + off);
#pragma unroll
    for (int j = 0; j < 4; ++j) mx[j] = fmaxf(mx[j], bf16_f(h[j]) + bf16_f(l[j]));
  }
  *(fx4*)(out + (size_t)g * F + (c << 2)) = mx;
}

// =========================== launch ========================================
extern "C" void kernel_launch(void* const* d_in, const int* in_sizes, int n_in,
                              void* d_out, int out_size, void* d_ws, size_t ws_size,
                              hipStream_t stream) {
  const float* x = (const float*)d_in[0];
  const int* edges = (const int*)d_in[1];
  const int* batch = (const int*)d_in[2];
  const int E = in_sizes[1] / 2;
  const int Nn = in_sizes[2];

  static const int FDS[4]  = {80, 160, 400, 600};
  static const int FDP[4]  = {96, 160, 416, 608};
  static const int DINS[4] = {3072, 80, 160, 400};
  static const int DINP[4] = {3072, 96, 160, 416};
  const float *wa[4], *ba[4], *wb[4], *bb[4], *gw[4], *gb[4], *gamma[4], *beta[4], *mean[4], *var[4];
  for (int i = 0; i < 4; ++i) {
    const int b = 3 + 10 * i;
    wa[i] = (const float*)d_in[b + 0];
    ba[i] = (const float*)d_in[b + 1];
    wb[i] = (const float*)d_in[b + 2];
    bb[i] = (const float*)d_in[b + 3];
    gw[i] = (const float*)d_in[b + 4];
    gb[i] = (const float*)d_in[b + 5];
    gamma[i] = (const float*)d_in[b + 6];
    beta[i] = (const float*)d_in[b + 7];
    mean[i] = (const float*)d_in[b + 8];
    var[i] = (const float*)d_in[b + 9];
  }

  char* p = (char*)d_ws;
  auto alloc = [&](size_t bytes) {
    char* r = p;
    p += (bytes + 255) & ~(size_t)255;
    return r;
  };
  u16* actA_h = (u16*)alloc((size_t)Nn * 2400 * 2);
  u16* actA_l = (u16*)alloc((size_t)Nn * 2400 * 2);
  u16* actB_h = (u16*)alloc((size_t)Nn * 608 * 2);
  u16* actB_l = (u16*)alloc((size_t)Nn * 608 * 2);
  float* H3 = (float*)actA_h;

  u16 *waT_h[4], *waT_l[4], *wbT_h[4], *wbT_l[4], *gwT_h[4], *gwT_l[4];
  for (int i = 0; i < 4; ++i) {
    const size_t s1 = (size_t)4 * FDS[i] * DINP[i];
    const size_t s2 = (size_t)FDS[i] * 4 * FDS[i];
    const size_t s3 = (size_t)FDS[i] * FDP[i];
    waT_h[i] = (u16*)alloc(s1 * 2);
    waT_l[i] = (u16*)alloc(s1 * 2);
    wbT_h[i] = (u16*)alloc(s2 * 2);
    wbT_l[i] = (u16*)alloc(s2 * 2);
    gwT_h[i] = (u16*)alloc(s3 * 2);
    gwT_l[i] = (u16*)alloc(s3 * 2);
  }

  int* cnt = (int*)alloc((size_t)Nn * sizeof(int));
  int* cursor = (int*)alloc((size_t)Nn * sizeof(int));
  int* partial = (int*)alloc((size_t)Nn * sizeof(int));
  int* blocksum = (int*)alloc(256 * sizeof(int));
  int* rowptr = (int*)alloc((size_t)(Nn + 1) * sizeof(int));
  int* colidx = (int*)alloc((size_t)E * sizeof(int));
  float* dinv = (float*)alloc((size_t)Nn * sizeof(float));

  const int* srcIdx = edges;
  const int* dstIdx = edges + E;

  {
    TSJobs jobs;
    int base = 0, ji = 0;
    auto addjob = [&](const float* W, int K, int Kp, int Ncols, u16* Th, u16* Tl) {
      const int tk = Kp / 32, tn = (Ncols + 31) / 32;
      jobs.j[ji++] = TSJob{W, Th, Tl, K, Kp, Ncols, tk, base};
      base += tk * tn;
    };
    for (int i = 0; i < 4; ++i) {
      addjob(wa[i], DINS[i], DINP[i], 4 * FDS[i], waT_h[i], waT_l[i]);
      addjob(wb[i], 4 * FDS[i], 4 * FDS[i], FDS[i], wbT_h[i], wbT_l[i]);
      addjob(gw[i], FDS[i], FDP[i], FDS[i], gwT_h[i], gwT_l[i]);
    }
    transpose_split_all<<<base, 256, 0, stream>>>(jobs, 12);
  }

  hipMemsetAsync(cnt, 0, (size_t)Nn * sizeof(int), stream);
  hipMemsetAsync(cursor, 0, (size_t)Nn * sizeof(int), stream);

  const int EB = (E + 255) / 256;
  const int NB = (Nn + 255) / 256;
  count_deg<<<EB, 256, 0, stream>>>(dstIdx, E, cnt);
  compute_dinv<<<NB, 256, 0, stream>>>(cnt, dinv, Nn);
  scan_block<<<NB, 256, 0, stream>>>(cnt, partial, blocksum, Nn);
  scan_sums<<<1, 256, 0, stream>>>(blocksum, NB);
  finalize_rowptr<<<NB, 256, 0, stream>>>(partial, blocksum, rowptr, Nn);
  fill_csr<<<EB, 256, 0, stream>>>(srcIdx, dstIdx, E, rowptr, cursor, colidx);

  const int tm = (Nn + 127) / 128;
  for (int i = 0; i < 4; ++i) {
    const int fd = FDS[i], fdp = FDP[i];
    const int hid = 4 * fd;
    const int din = DINS[i], dinp = DINP[i];

    // G1: X @ wa + ba, relu -> H1 (split, ldc = hid)
    {
      const int tn = (hid + 127) / 128;
      if (i == 0) {
        gemm_splita<<<tm * tn, 256, 0, stream>>>(
            x, waT_h[0], waT_l[0], ba[0],
            actA_h, actA_l, Nn, hid, din, din, dinp, hid, tm, tn);
      } else {
        gemm_ph<1><<<tm * tn, 256, 0, stream>>>(
            actB_h, actB_l, waT_h[i], waT_l[i], ba[i],
            nullptr, actA_h, actA_l, Nn, hid, din, dinp, dinp, hid, tm, tn);
      }
    }
    // G2: H1 @ wb + bb, relu -> H2 (split, ldc = fdp, zero pads)
    {
      const int tn = (fd + 127) / 128;
      gemm_ph<1><<<tm * tn, 256, 0, stream>>>(
          actA_h, actA_l, wbT_h[i], wbT_l[i], bb[i],
          nullptr, actB_h, actB_l, Nn, fd, hid, hid, hid, fdp, tm, tn);
    }
    // G3: H2 @ gw -> H3 (fp32, ldc = fdp, zero pads)
    {
      const int tn = (fd + 127) / 128;
      gemm_ph<0><<<tm * tn, 256, 0, stream>>>(
          actB_h, actB_l, gwT_h[i], gwT_l[i], nullptr,
          H3, nullptr, nullptr, Nn, fd, fd, fdp, fdp, fdp, tm, tn);
    }
    // MP + bias + BN + ReLU -> X_next
    {
      const int items = Nn * (fdp >> 2);
      mp_bn_relu<<<(items + 255) / 256, 256, 0, stream>>>(
          H3, rowptr, colidx, dinv, gb[i], gamma[i], beta[i], mean[i], var[i],
          actB_h, actB_l, Nn, fd, fdp);
    }
  }

  pool_seg<<<out_size / 600, 192, 0, stream>>>(actB_h, actB_l, batch, (float*)d_out,
                                               Nn, 600, 608);
}

// Round 10
// 1793.629 us; speedup vs baseline: 1.0315x; 1.0315x over previous
//
#include <hip/hip_runtime.h>
#include <cstdint>
#include <cstddef>
#include <cmath>

// ---------------------------------------------------------------------------
// Round 11: measured-best composite.
// 5-structure sweep (R6/R7/R8/R9/R10b) showed: R7's dbuf 1-deep body has the
// fastest gemm dispatch (248us vs 266 R6, 271 R10b) but R7's SPLITA variant
// regressed the layer-0 GEMM; R6's simple SPLITA was best-in-total. This
// round combines them: gemm_ph = R7 dbuf body (1 barrier/K-step, prefetch
// issued post-barrier), gemm_splita = R6 single-buffer body. 4-phase (R10b)
// abandoned per m196 (coarse split without fine interleave = convoy cost).
// ---------------------------------------------------------------------------

#define EPS_BN 1e-5f

typedef unsigned short u16;
typedef short short8 __attribute__((ext_vector_type(8)));
typedef u16 u16x8 __attribute__((ext_vector_type(8)));
typedef u16 u16x4 __attribute__((ext_vector_type(4)));
typedef float fx4 __attribute__((ext_vector_type(4)));

__device__ __forceinline__ u16 bf16_rn(float f) {
  unsigned u = __float_as_uint(f);
  return (u16)((u + 0x7FFFu + ((u >> 16) & 1u)) >> 16);
}
__device__ __forceinline__ float bf16_f(u16 h) {
  return __uint_as_float(((unsigned)h) << 16);
}

// async global->LDS, 16B per lane; LDS dest = wave-uniform base + lane*16
__device__ __forceinline__ void gload16(const void* g, void* l) {
  __builtin_amdgcn_global_load_lds(
      (const __attribute__((address_space(1))) void*)g,
      (__attribute__((address_space(3))) void*)l, 16, 0, 0);
}

// ---- XCD-ownership swizzle: bijection blockIdx -> (mt, nt) ----------------
__device__ __forceinline__ void map_tile(int b, int tm, int tn, int T,
                                         int& mt, int& nt) {
  const int x = b & 7;
  const int s = b >> 3;
  const int cap = ((tm - x + 7) >> 3) * tn;  // slots in x's owned region
  if (s < cap) {
    const int q = s / tn;
    mt = x + (q << 3);
    nt = s - q * tn;
    return;
  }
  int r = s - cap;  // overflow rank (within this XCD's overflow)
  for (int xp = 0; xp < x; ++xp) {
    const int nbp = (T - xp + 7) >> 3;
    const int capp = ((tm - xp + 7) >> 3) * tn;
    if (nbp > capp) r += nbp - capp;
  }
  for (int xq = 0; xq < 8; ++xq) {
    const int nbq = (T - xq + 7) >> 3;
    const int capq = ((tm - xq + 7) >> 3) * tn;
    const int def = capq - nbq;
    if (def > 0) {
      if (r < def) {
        const int sq = nbq + r;
        const int q = sq / tn;
        mt = xq + (q << 3);
        nt = sq - q * tn;
        return;
      }
      r -= def;
    }
  }
  mt = 0; nt = 0;  // unreachable
}

// ============== dbuf GEMM (split-bf16 A and B inputs), R7 body =============
// C(MxN) = act(A @ B + bias). Ahi/Alo: M x K bf16 (lda, K-pads = 0).
// Bhi/Blo: N x K bf16 (ldb, K-pads = 0). OUTMODE 0: fp32 C (zero pad cols);
// OUTMODE 1: bias+relu -> split bf16. Block 128x128, BK=32, 4 waves (2x2),
// wave 64x64 as 4x4 MFMA 16x16x32; 3 MFMAs (hihi, hilo, lohi).
// Double-buffered: prefetch of tile ki+1 issued AFTER the per-iter barrier,
// so the barrier's vmcnt(0) drain only waits on loads issued one full
// compute phase earlier. One barrier per K-step.
template <int OUTMODE>
__global__ __launch_bounds__(256, 2) void gemm_ph(
    const u16* __restrict__ Ahi, const u16* __restrict__ Alo,
    const u16* __restrict__ Bhi, const u16* __restrict__ Blo,
    const float* __restrict__ bias,
    float* __restrict__ Cf, u16* __restrict__ Chi, u16* __restrict__ Clo,
    int M, int N, int K, int lda, int ldb, int ldc, int tm, int tn) {
  __shared__ __align__(16) u16 As[2][2][128 * 32];  // [buf][hi/lo]
  __shared__ __align__(16) u16 Bs[2][2][128 * 32];

  int mt, nt;
  map_tile(blockIdx.x, tm, tn, tm * tn, mt, nt);
  const int m0 = mt * 128;
  const int n0 = nt * 128;

  const int tid = threadIdx.x;
  const int lane = tid & 63;
  const int wid = tid >> 6;
  const int wm = (wid >> 1) * 64;
  const int wn = (wid & 1) * 64;
  const int quad = lane >> 4;
  const int l15 = lane & 15;

  // staging: thread -> (row = tid>>2, 16B slot = tid&3), slot hash f(row)
  const int srow = tid >> 2;
  const int sg = ((tid & 3) ^ srow ^ (srow >> 2)) & 3;
  int ar0 = m0 + srow;      if (ar0 >= M) ar0 = M - 1;   // clamp: finite data,
  int ar1 = m0 + srow + 64; if (ar1 >= M) ar1 = M - 1;   // results discarded
  int br0 = n0 + srow;      if (br0 >= N) br0 = N - 1;
  int br1 = n0 + srow + 64; if (br1 >= N) br1 = N - 1;
  const size_t aof0 = (size_t)ar0 * lda + (sg << 3);
  const size_t aof1 = (size_t)ar1 * lda + (sg << 3);
  const size_t bof0 = (size_t)br0 * ldb + (sg << 3);
  const size_t bof1 = (size_t)br1 * ldb + (sg << 3);
  const int l0 = wid << 9;           // wave-uniform LDS base, u16 units
  const int l1 = 2048 + (wid << 9);  // rows 64..127 region

  fx4 zf = {0.f, 0.f, 0.f, 0.f};
  fx4 acc[4][4];
#pragma unroll
  for (int a = 0; a < 4; ++a)
#pragma unroll
    for (int b = 0; b < 4; ++b) acc[a][b] = zf;

  const int nk = (K + 31) >> 5;

  // ---- prologue: stage tile 0 into buf 0 ----
  gload16(Ahi + aof0, &As[0][0][l0]);
  gload16(Ahi + aof1, &As[0][0][l1]);
  gload16(Alo + aof0, &As[0][1][l0]);
  gload16(Alo + aof1, &As[0][1][l1]);
  gload16(Bhi + bof0, &Bs[0][0][l0]);
  gload16(Bhi + bof1, &Bs[0][0][l1]);
  gload16(Blo + bof0, &Bs[0][1][l0]);
  gload16(Blo + bof1, &Bs[0][1][l1]);

  for (int ki = 0; ki < nk; ++ki) {
    const int cur = ki & 1;
    // drains tile-ki loads (issued one full compute phase ago)
    __syncthreads();

    if (ki + 1 < nk) {
      const size_t kn = (size_t)(ki + 1) << 5;
      gload16(Ahi + aof0 + kn, &As[cur ^ 1][0][l0]);
      gload16(Ahi + aof1 + kn, &As[cur ^ 1][0][l1]);
      gload16(Alo + aof0 + kn, &As[cur ^ 1][1][l0]);
      gload16(Alo + aof1 + kn, &As[cur ^ 1][1][l1]);
      gload16(Bhi + bof0 + kn, &Bs[cur ^ 1][0][l0]);
      gload16(Bhi + bof1 + kn, &Bs[cur ^ 1][0][l1]);
      gload16(Blo + bof0 + kn, &Bs[cur ^ 1][1][l0]);
      gload16(Blo + bof1 + kn, &Bs[cur ^ 1][1][l1]);
    }

    // frag reads from buf[cur] (read-side swizzle matches staged source swz)
    short8 ah[4], al[4], bh[4], bl[4];
#pragma unroll
    for (int t = 0; t < 4; ++t) {
      const int rA = wm + t * 16 + l15;
      const int oa = rA * 32 + (((quad ^ rA ^ (rA >> 2)) & 3) << 3);
      ah[t] = *(const short8*)&As[cur][0][oa];
      al[t] = *(const short8*)&As[cur][1][oa];
      const int rB = wn + t * 16 + l15;
      const int ob = rB * 32 + (((quad ^ rB ^ (rB >> 2)) & 3) << 3);
      bh[t] = *(const short8*)&Bs[cur][0][ob];
      bl[t] = *(const short8*)&Bs[cur][1][ob];
    }
#pragma unroll
    for (int a = 0; a < 4; ++a)
#pragma unroll
      for (int b = 0; b < 4; ++b) {
        acc[a][b] = __builtin_amdgcn_mfma_f32_16x16x32_bf16(ah[a], bh[b], acc[a][b], 0, 0, 0);
        acc[a][b] = __builtin_amdgcn_mfma_f32_16x16x32_bf16(ah[a], bl[b], acc[a][b], 0, 0, 0);
        acc[a][b] = __builtin_amdgcn_mfma_f32_16x16x32_bf16(al[a], bh[b], acc[a][b], 0, 0, 0);
      }
  }

#pragma unroll
  for (int a = 0; a < 4; ++a)
#pragma unroll
    for (int b = 0; b < 4; ++b) {
      const int gn = n0 + wn + b * 16 + l15;
      if (gn >= ldc) continue;
      const bool live = gn < N;
      const float bv = (OUTMODE == 1 && live) ? bias[gn] : 0.f;
#pragma unroll
      for (int r = 0; r < 4; ++r) {
        const int gm = m0 + wm + a * 16 + quad * 4 + r;
        if (gm >= M) continue;
        float v = live ? acc[a][b][r] : 0.f;
        if (OUTMODE == 1) {
          v = live ? fmaxf(v + bv, 0.f) : 0.f;
          const u16 hb = bf16_rn(v);
          Chi[(size_t)gm * ldc + gn] = hb;
          Clo[(size_t)gm * ldc + gn] = bf16_rn(v - bf16_f(hb));
        } else {
          Cf[(size_t)gm * ldc + gn] = v;
        }
      }
    }
}

// ================= R6-path GEMM for fp32-A (layer-0 G1 only) ===============
__global__ __launch_bounds__(256, 2) void gemm_splita(
    const float* __restrict__ Af,
    const u16* __restrict__ Bhi, const u16* __restrict__ Blo,
    const float* __restrict__ bias,
    u16* __restrict__ Chi, u16* __restrict__ Clo,
    int M, int N, int K, int lda, int ldb, int ldc, int tm, int tn) {
  __shared__ __align__(16) u16 As[2][128 * 32];
  __shared__ __align__(16) u16 Bs[2][128 * 32];

  int mt, nt;
  map_tile(blockIdx.x, tm, tn, tm * tn, mt, nt);
  const int m0 = mt * 128;
  const int n0 = nt * 128;

  const int tid = threadIdx.x;
  const int lane = tid & 63;
  const int wid = tid >> 6;
  const int wm = (wid >> 1) * 64;
  const int wn = (wid & 1) * 64;
  const int quad = lane >> 4;
  const int l15 = lane & 15;

  const int srow = tid >> 2;
  const int sg = ((tid & 3) ^ srow ^ (srow >> 2)) & 3;
  int ar0 = m0 + srow;      if (ar0 >= M) ar0 = M - 1;
  int ar1 = m0 + srow + 64; if (ar1 >= M) ar1 = M - 1;
  int br0 = n0 + srow;      if (br0 >= N) br0 = N - 1;
  int br1 = n0 + srow + 64; if (br1 >= N) br1 = N - 1;
  const size_t aof0 = (size_t)ar0 * lda + (sg << 3);
  const size_t aof1 = (size_t)ar1 * lda + (sg << 3);
  const size_t bof0 = (size_t)br0 * ldb + (sg << 3);
  const size_t bof1 = (size_t)br1 * ldb + (sg << 3);
  const int l0 = wid << 9;
  const int l1 = 2048 + (wid << 9);
  const int wls = srow * 32 + ((tid & 3) << 3);

  fx4 zf = {0.f, 0.f, 0.f, 0.f};
  fx4 acc[4][4];
#pragma unroll
  for (int a = 0; a < 4; ++a)
#pragma unroll
    for (int b = 0; b < 4; ++b) acc[a][b] = zf;

  const int nk = (K + 31) >> 5;
  for (int ki = 0; ki < nk; ++ki) {
    const int k0 = ki << 5;
    u16x8 va_h[2], va_l[2];
#pragma unroll
    for (int it = 0; it < 2; ++it) {
      const float* pp = Af + (it ? aof1 : aof0) + k0;
      const fx4 f0 = *(const fx4*)pp;
      const fx4 f1 = *(const fx4*)(pp + 4);
      u16x8 h, l;
#pragma unroll
      for (int j = 0; j < 4; ++j) {
        const u16 hb = bf16_rn(f0[j]);
        h[j] = hb;
        l[j] = bf16_rn(f0[j] - bf16_f(hb));
      }
#pragma unroll
      for (int j = 0; j < 4; ++j) {
        const u16 hb = bf16_rn(f1[j]);
        h[4 + j] = hb;
        l[4 + j] = bf16_rn(f1[j] - bf16_f(hb));
      }
      va_h[it] = h;
      va_l[it] = l;
    }

    if (ki) __syncthreads();

    gload16(Bhi + bof0 + k0, &Bs[0][l0]);
    gload16(Bhi + bof1 + k0, &Bs[0][l1]);
    gload16(Blo + bof0 + k0, &Bs[1][l0]);
    gload16(Blo + bof1 + k0, &Bs[1][l1]);
    *(u16x8*)&As[0][wls] = va_h[0];
    *(u16x8*)&As[0][wls + 2048] = va_h[1];
    *(u16x8*)&As[1][wls] = va_l[0];
    *(u16x8*)&As[1][wls + 2048] = va_l[1];
    __syncthreads();

    short8 ah[4], al[4], bh[4], bl[4];
#pragma unroll
    for (int t = 0; t < 4; ++t) {
      const int rA = wm + t * 16 + l15;
      const int oa = rA * 32 + (((quad ^ rA ^ (rA >> 2)) & 3) << 3);
      ah[t] = *(const short8*)&As[0][oa];
      al[t] = *(const short8*)&As[1][oa];
      const int rB = wn + t * 16 + l15;
      const int ob = rB * 32 + (((quad ^ rB ^ (rB >> 2)) & 3) << 3);
      bh[t] = *(const short8*)&Bs[0][ob];
      bl[t] = *(const short8*)&Bs[1][ob];
    }
#pragma unroll
    for (int a = 0; a < 4; ++a)
#pragma unroll
      for (int b = 0; b < 4; ++b) {
        acc[a][b] = __builtin_amdgcn_mfma_f32_16x16x32_bf16(ah[a], bh[b], acc[a][b], 0, 0, 0);
        acc[a][b] = __builtin_amdgcn_mfma_f32_16x16x32_bf16(ah[a], bl[b], acc[a][b], 0, 0, 0);
        acc[a][b] = __builtin_amdgcn_mfma_f32_16x16x32_bf16(al[a], bh[b], acc[a][b], 0, 0, 0);
      }
  }

#pragma unroll
  for (int a = 0; a < 4; ++a)
#pragma unroll
    for (int b = 0; b < 4; ++b) {
      const int gn = n0 + wn + b * 16 + l15;
      if (gn >= ldc) continue;
      const bool live = gn < N;
      const float bv = live ? bias[gn] : 0.f;
#pragma unroll
      for (int r = 0; r < 4; ++r) {
        const int gm = m0 + wm + a * 16 + quad * 4 + r;
        if (gm < M) {
          float v = live ? fmaxf(acc[a][b][r] + bv, 0.f) : 0.f;
          const u16 hb = bf16_rn(v);
          Chi[(size_t)gm * ldc + gn] = hb;
          Clo[(size_t)gm * ldc + gn] = bf16_rn(v - bf16_f(hb));
        }
      }
    }
}

// ================= weight prep: transpose + split (batched) ================
struct TSJob { const float* W; u16* Th; u16* Tl; int K; int Kp; int N; int tiles_k; int base; };
struct TSJobs { TSJob j[12]; };

__global__ __launch_bounds__(256) void transpose_split_all(TSJobs jobs, int njobs) {
  const int b = blockIdx.x;
  int ji = 0;
  while (ji + 1 < njobs && jobs.j[ji + 1].base <= b) ++ji;
  const TSJob J = jobs.j[ji];
  const int t = b - J.base;
  const int k0 = (t % J.tiles_k) * 32;
  const int n0 = (t / J.tiles_k) * 32;
  __shared__ float tile[32][33];
  const int tx = threadIdx.x & 31, ty = threadIdx.x >> 5;
#pragma unroll
  for (int i = 0; i < 32; i += 8) {
    const int k = k0 + ty + i, n = n0 + tx;
    tile[ty + i][tx] = (k < J.K && n < J.N) ? J.W[(size_t)k * J.N + n] : 0.f;
  }
  __syncthreads();
#pragma unroll
  for (int i = 0; i < 32; i += 8) {
    const int n = n0 + ty + i, k = k0 + tx;
    if (n < J.N && k < J.Kp) {
      const float f = tile[tx][ty + i];
      const u16 hb = bf16_rn(f);
      J.Th[(size_t)n * J.Kp + k] = hb;
      J.Tl[(size_t)n * J.Kp + k] = bf16_rn(f - bf16_f(hb));
    }
  }
}

// ========================= Graph preprocessing =============================
__global__ void count_deg(const int* __restrict__ dst, int E, int* __restrict__ cnt) {
  int e = blockIdx.x * blockDim.x + threadIdx.x;
  if (e < E) atomicAdd(&cnt[dst[e]], 1);
}

__global__ void compute_dinv(const int* __restrict__ cnt, float* __restrict__ dinv, int N) {
  int i = blockIdx.x * blockDim.x + threadIdx.x;
  if (i < N) dinv[i] = rsqrtf((float)(cnt[i] + 1));
}

__global__ void scan_block(const int* __restrict__ cnt, int* __restrict__ partial,
                           int* __restrict__ blocksum, int N) {
  __shared__ int s[256];
  const int t = threadIdx.x;
  const int i = blockIdx.x * 256 + t;
  int v = (i < N) ? cnt[i] : 0;
  s[t] = v;
  __syncthreads();
  for (int off = 1; off < 256; off <<= 1) {
    int u = (t >= off) ? s[t - off] : 0;
    __syncthreads();
    s[t] += u;
    __syncthreads();
  }
  if (i < N) partial[i] = s[t];
  if (t == 255) blocksum[blockIdx.x] = s[255];
}

__global__ void scan_sums(int* __restrict__ blocksum, int NB) {
  __shared__ int s[256];
  const int t = threadIdx.x;
  int v = (t < NB) ? blocksum[t] : 0;
  s[t] = v;
  __syncthreads();
  for (int off = 1; off < 256; off <<= 1) {
    int u = (t >= off) ? s[t - off] : 0;
    __syncthreads();
    s[t] += u;
    __syncthreads();
  }
  if (t < NB) blocksum[t] = s[t] - v;
}

__global__ void finalize_rowptr(const int* __restrict__ partial, const int* __restrict__ blockoff,
                                int* __restrict__ rowptr, int N) {
  int i = blockIdx.x * 256 + threadIdx.x;
  if (i < N) rowptr[i + 1] = partial[i] + blockoff[blockIdx.x];
  if (i == 0) rowptr[0] = 0;
}

__global__ void fill_csr(const int* __restrict__ src, const int* __restrict__ dst, int E,
                         const int* __restrict__ rowptr, int* __restrict__ cursor,
                         int* __restrict__ colidx) {
  int e = blockIdx.x * blockDim.x + threadIdx.x;
  if (e < E) {
    int d = dst[e];
    int p = atomicAdd(&cursor[d], 1);
    colidx[rowptr[d] + p] = src[e];
  }
}

// ================= Message passing + bias + BN + ReLU ======================
__global__ void mp_bn_relu(
    const float* __restrict__ H, const int* __restrict__ rowptr,
    const int* __restrict__ colidx, const float* __restrict__ dinv,
    const float* __restrict__ gb, const float* __restrict__ gamma,
    const float* __restrict__ beta, const float* __restrict__ mean,
    const float* __restrict__ var,
    u16* __restrict__ Xh, u16* __restrict__ Xl, int N, int F, int Fp) {
  const int nch = Fp >> 2;
  const int idx = blockIdx.x * blockDim.x + threadIdx.x;
  if (idx >= N * nch) return;
  const int i = idx / nch;
  const int c = idx - i * nch;
  const size_t rowi = (size_t)i * Fp + (c << 2);
  if ((c << 2) >= F) {
    const u16x4 z = {0, 0, 0, 0};
    *(u16x4*)(Xh + rowi) = z;
    *(u16x4*)(Xl + rowi) = z;
    return;
  }
  const float di = dinv[i];
  fx4 acc = (di * di) * *(const fx4*)(H + rowi);
  const int e0 = rowptr[i], e1 = rowptr[i + 1];
  int e = e0;
  for (; e + 4 <= e1; e += 4) {
    const int s0 = colidx[e + 0], s1 = colidx[e + 1];
    const int s2 = colidx[e + 2], s3 = colidx[e + 3];
    const float w0 = di * dinv[s0], w1 = di * dinv[s1];
    const float w2 = di * dinv[s2], w3 = di * dinv[s3];
    const fx4 v0 = *(const fx4*)(H + (size_t)s0 * Fp + (c << 2));
    const fx4 v1 = *(const fx4*)(H + (size_t)s1 * Fp + (c << 2));
    const fx4 v2 = *(const fx4*)(H + (size_t)s2 * Fp + (c << 2));
    const fx4 v3 = *(const fx4*)(H + (size_t)s3 * Fp + (c << 2));
    acc += w0 * v0;
    acc += w1 * v1;
    acc += w2 * v2;
    acc += w3 * v3;
  }
  for (; e < e1; ++e) {
    const int s = colidx[e];
    acc += (di * dinv[s]) * *(const fx4*)(H + (size_t)s * Fp + (c << 2));
  }
  u16x4 oh, ol;
#pragma unroll
  for (int j = 0; j < 4; ++j) {
    const int col = (c << 2) + j;
    float v = (acc[j] + gb[col] - mean[col]) * rsqrtf(var[col] + EPS_BN) * gamma[col] + beta[col];
    v = fmaxf(v, 0.f);
    const u16 hb = bf16_rn(v);
    oh[j] = hb;
    ol[j] = bf16_rn(v - bf16_f(hb));
  }
  *(u16x4*)(Xh + rowi) = oh;
  *(u16x4*)(Xl + rowi) = ol;
}

// ========================= global max pool (segments) ======================
__global__ void pool_seg(const u16* __restrict__ Xh, const u16* __restrict__ Xl,
                         const int* __restrict__ batch, float* __restrict__ out,
                         int N, int F, int ldx) {
  const int g = blockIdx.x;
  int lo = 0, hi = N;
  while (lo < hi) { int m = (lo + hi) >> 1; if (batch[m] < g) lo = m + 1; else hi = m; }
  const int s0 = lo;
  hi = N;
  while (lo < hi) { int m = (lo + hi) >> 1; if (batch[m] <= g) lo = m + 1; else hi = m; }
  const int s1 = lo;
  const int c = threadIdx.x;
  if (c * 4 >= F) return;
  fx4 mx = {-INFINITY, -INFINITY, -INFINITY, -INFINITY};
  for (int i = s0; i < s1; ++i) {
    const size_t off = (size_t)i * ldx + (c << 2);
    const u16x4 h = *(const u16x4*)(Xh + off);
    const u16x4 l = *(const u16x4*)(Xl + off);
#pragma unroll
    for (int j = 0; j < 4; ++j) mx[j] = fmaxf(mx[j], bf16_f(h[j]) + bf16_f(l[j]));
  }
  *(fx4*)(out + (size_t)g * F + (c << 2)) = mx;
}

// =========================== launch ========================================
extern "C" void kernel_launch(void* const* d_in, const int* in_sizes, int n_in,
                              void* d_out, int out_size, void* d_ws, size_t ws_size,
                              hipStream_t stream) {
  const float* x = (const float*)d_in[0];
  const int* edges = (const int*)d_in[1];
  const int* batch = (const int*)d_in[2];
  const int E = in_sizes[1] / 2;
  const int Nn = in_sizes[2];

  static const int FDS[4]  = {80, 160, 400, 600};
  static const int FDP[4]  = {96, 160, 416, 608};
  static const int DINS[4] = {3072, 80, 160, 400};
  static const int DINP[4] = {3072, 96, 160, 416};
  const float *wa[4], *ba[4], *wb[4], *bb[4], *gw[4], *gb[4], *gamma[4], *beta[4], *mean[4], *var[4];
  for (int i = 0; i < 4; ++i) {
    const int b = 3 + 10 * i;
    wa[i] = (const float*)d_in[b + 0];
    ba[i] = (const float*)d_in[b + 1];
    wb[i] = (const float*)d_in[b + 2];
    bb[i] = (const float*)d_in[b + 3];
    gw[i] = (const float*)d_in[b + 4];
    gb[i] = (const float*)d_in[b + 5];
    gamma[i] = (const float*)d_in[b + 6];
    beta[i] = (const float*)d_in[b + 7];
    mean[i] = (const float*)d_in[b + 8];
    var[i] = (const float*)d_in[b + 9];
  }

  char* p = (char*)d_ws;
  auto alloc = [&](size_t bytes) {
    char* r = p;
    p += (bytes + 255) & ~(size_t)255;
    return r;
  };
  u16* actA_h = (u16*)alloc((size_t)Nn * 2400 * 2);
  u16* actA_l = (u16*)alloc((size_t)Nn * 2400 * 2);
  u16* actB_h = (u16*)alloc((size_t)Nn * 608 * 2);
  u16* actB_l = (u16*)alloc((size_t)Nn * 608 * 2);
  float* H3 = (float*)actA_h;

  u16 *waT_h[4], *waT_l[4], *wbT_h[4], *wbT_l[4], *gwT_h[4], *gwT_l[4];
  for (int i = 0; i < 4; ++i) {
    const size_t s1 = (size_t)4 * FDS[i] * DINP[i];
    const size_t s2 = (size_t)FDS[i] * 4 * FDS[i];
    const size_t s3 = (size_t)FDS[i] * FDP[i];
    waT_h[i] = (u16*)alloc(s1 * 2);
    waT_l[i] = (u16*)alloc(s1 * 2);
    wbT_h[i] = (u16*)alloc(s2 * 2);
    wbT_l[i] = (u16*)alloc(s2 * 2);
    gwT_h[i] = (u16*)alloc(s3 * 2);
    gwT_l[i] = (u16*)alloc(s3 * 2);
  }

  int* cnt = (int*)alloc((size_t)Nn * sizeof(int));
  int* cursor = (int*)alloc((size_t)Nn * sizeof(int));
  int* partial = (int*)alloc((size_t)Nn * sizeof(int));
  int* blocksum = (int*)alloc(256 * sizeof(int));
  int* rowptr = (int*)alloc((size_t)(Nn + 1) * sizeof(int));
  int* colidx = (int*)alloc((size_t)E * sizeof(int));
  float* dinv = (float*)alloc((size_t)Nn * sizeof(float));

  const int* srcIdx = edges;
  const int* dstIdx = edges + E;

  {
    TSJobs jobs;
    int base = 0, ji = 0;
    auto addjob = [&](const float* W, int K, int Kp, int Ncols, u16* Th, u16* Tl) {
      const int tk = Kp / 32, tn = (Ncols + 31) / 32;
      jobs.j[ji++] = TSJob{W, Th, Tl, K, Kp, Ncols, tk, base};
      base += tk * tn;
    };
    for (int i = 0; i < 4; ++i) {
      addjob(wa[i], DINS[i], DINP[i], 4 * FDS[i], waT_h[i], waT_l[i]);
      addjob(wb[i], 4 * FDS[i], 4 * FDS[i], FDS[i], wbT_h[i], wbT_l[i]);
      addjob(gw[i], FDS[i], FDP[i], FDS[i], gwT_h[i], gwT_l[i]);
    }
    transpose_split_all<<<base, 256, 0, stream>>>(jobs, 12);
  }

  hipMemsetAsync(cnt, 0, (size_t)Nn * sizeof(int), stream);
  hipMemsetAsync(cursor, 0, (size_t)Nn * sizeof(int), stream);

  const int EB = (E + 255) / 256;
  const int NB = (Nn + 255) / 256;
  count_deg<<<EB, 256, 0, stream>>>(dstIdx, E, cnt);
  compute_dinv<<<NB, 256, 0, stream>>>(cnt, dinv, Nn);
  scan_block<<<NB, 256, 0, stream>>>(cnt, partial, blocksum, Nn);
  scan_sums<<<1, 256, 0, stream>>>(blocksum, NB);
  finalize_rowptr<<<NB, 256, 0, stream>>>(partial, blocksum, rowptr, Nn);
  fill_csr<<<EB, 256, 0, stream>>>(srcIdx, dstIdx, E, rowptr, cursor, colidx);

  const int tm = (Nn + 127) / 128;
  for (int i = 0; i < 4; ++i) {
    const int fd = FDS[i], fdp = FDP[i];
    const int hid = 4 * fd;
    const int din = DINS[i], dinp = DINP[i];

    // G1: X @ wa + ba, relu -> H1 (split, ldc = hid)
    {
      const int tn = (hid + 127) / 128;
      if (i == 0) {
        gemm_splita<<<tm * tn, 256, 0, stream>>>(
            x, waT_h[0], waT_l[0], ba[0],
            actA_h, actA_l, Nn, hid, din, din, dinp, hid, tm, tn);
      } else {
        gemm_ph<1><<<tm * tn, 256, 0, stream>>>(
            actB_h, actB_l, waT_h[i], waT_l[i], ba[i],
            nullptr, actA_h, actA_l, Nn, hid, din, dinp, dinp, hid, tm, tn);
      }
    }
    // G2: H1 @ wb + bb, relu -> H2 (split, ldc = fdp, zero pads)
    {
      const int tn = (fd + 127) / 128;
      gemm_ph<1><<<tm * tn, 256, 0, stream>>>(
          actA_h, actA_l, wbT_h[i], wbT_l[i], bb[i],
          nullptr, actB_h, actB_l, Nn, fd, hid, hid, hid, fdp, tm, tn);
    }
    // G3: H2 @ gw -> H3 (fp32, ldc = fdp, zero pads)
    {
      const int tn = (fd + 127) / 128;
      gemm_ph<0><<<tm * tn, 256, 0, stream>>>(
          actB_h, actB_l, gwT_h[i], gwT_l[i], nullptr,
          H3, nullptr, nullptr, Nn, fd, fd, fdp, fdp, fdp, tm, tn);
    }
    // MP + bias + BN + ReLU -> X_next
    {
      const int items = Nn * (fdp >> 2);
      mp_bn_relu<<<(items + 255) / 256, 256, 0, stream>>>(
          H3, rowptr, colidx, dinv, gb[i], gamma[i], beta[i], mean[i], var[i],
          actB_h, actB_l, Nn, fd, fdp);
    }
  }

  pool_seg<<<out_size / 600, 192, 0, stream>>>(actB_h, actB_l, batch, (float*)d_out,
                                               Nn, 600, 608);
}

// Round 11
// 1716.247 us; speedup vs baseline: 1.0780x; 1.0451x over previous
//
#include <hip/hip_runtime.h>
#include <cstdint>
#include <cstddef>
#include <cmath>

// ---------------------------------------------------------------------------
// Round 12: per-dispatch structure selection from the measured R6/R7/R11 data.
// Facts: dbuf body (64KB LDS, 2 blocks/CU) wins on long-K dispatches
// (L3-G2: 266->251us) but loses ~26% on short-K ones (inter-block overlap
// beats intra-block pipelining when nk small); single-buffer (32KB, up to
// 5 blocks/CU) is best elsewhere; dbuf-SPLITA is neutral (R7 vs R11: 2us).
// => gemm_db (R7 body) for K>=1280 (L3-G2, L2-G2); gemm_sb (R6/R9 body)
// for the other 9 gemm dispatches; gemm_splita (R6 body) for layer-0 G1.
// All kernel bodies bit-identical to harness-verified rounds.
// ---------------------------------------------------------------------------

#define EPS_BN 1e-5f

typedef unsigned short u16;
typedef short short8 __attribute__((ext_vector_type(8)));
typedef u16 u16x8 __attribute__((ext_vector_type(8)));
typedef u16 u16x4 __attribute__((ext_vector_type(4)));
typedef float fx4 __attribute__((ext_vector_type(4)));

__device__ __forceinline__ u16 bf16_rn(float f) {
  unsigned u = __float_as_uint(f);
  return (u16)((u + 0x7FFFu + ((u >> 16) & 1u)) >> 16);
}
__device__ __forceinline__ float bf16_f(u16 h) {
  return __uint_as_float(((unsigned)h) << 16);
}

// async global->LDS, 16B per lane; LDS dest = wave-uniform base + lane*16
__device__ __forceinline__ void gload16(const void* g, void* l) {
  __builtin_amdgcn_global_load_lds(
      (const __attribute__((address_space(1))) void*)g,
      (__attribute__((address_space(3))) void*)l, 16, 0, 0);
}

// ---- XCD-ownership swizzle: bijection blockIdx -> (mt, nt) ----------------
__device__ __forceinline__ void map_tile(int b, int tm, int tn, int T,
                                         int& mt, int& nt) {
  const int x = b & 7;
  const int s = b >> 3;
  const int cap = ((tm - x + 7) >> 3) * tn;  // slots in x's owned region
  if (s < cap) {
    const int q = s / tn;
    mt = x + (q << 3);
    nt = s - q * tn;
    return;
  }
  int r = s - cap;  // overflow rank (within this XCD's overflow)
  for (int xp = 0; xp < x; ++xp) {
    const int nbp = (T - xp + 7) >> 3;
    const int capp = ((tm - xp + 7) >> 3) * tn;
    if (nbp > capp) r += nbp - capp;
  }
  for (int xq = 0; xq < 8; ++xq) {
    const int nbq = (T - xq + 7) >> 3;
    const int capq = ((tm - xq + 7) >> 3) * tn;
    const int def = capq - nbq;
    if (def > 0) {
      if (r < def) {
        const int sq = nbq + r;
        const int q = sq / tn;
        mt = xq + (q << 3);
        nt = sq - q * tn;
        return;
      }
      r -= def;
    }
  }
  mt = 0; nt = 0;  // unreachable
}

// ============ single-buffer GEMM (R6/R9 body) — short/mid-K path ===========
// C(MxN) = act(A @ B + bias). Ahi/Alo: M x K bf16 (lda, K-pads = 0).
// Bhi/Blo: N x K bf16 (ldb, K-pads = 0). OUTMODE 0: fp32 C (zero pad cols);
// OUTMODE 1: bias+relu -> split bf16. 128x128x32, 4 waves, 32KB LDS.
template <int OUTMODE>
__global__ __launch_bounds__(256, 2) void gemm_sb(
    const u16* __restrict__ Ahi, const u16* __restrict__ Alo,
    const u16* __restrict__ Bhi, const u16* __restrict__ Blo,
    const float* __restrict__ bias,
    float* __restrict__ Cf, u16* __restrict__ Chi, u16* __restrict__ Clo,
    int M, int N, int K, int lda, int ldb, int ldc, int tm, int tn) {
  __shared__ __align__(16) u16 As[2][128 * 32];
  __shared__ __align__(16) u16 Bs[2][128 * 32];

  int mt, nt;
  map_tile(blockIdx.x, tm, tn, tm * tn, mt, nt);
  const int m0 = mt * 128;
  const int n0 = nt * 128;

  const int tid = threadIdx.x;
  const int lane = tid & 63;
  const int wid = tid >> 6;
  const int wm = (wid >> 1) * 64;
  const int wn = (wid & 1) * 64;
  const int quad = lane >> 4;
  const int l15 = lane & 15;

  const int srow = tid >> 2;
  const int sg = ((tid & 3) ^ srow ^ (srow >> 2)) & 3;
  int ar0 = m0 + srow;      if (ar0 >= M) ar0 = M - 1;
  int ar1 = m0 + srow + 64; if (ar1 >= M) ar1 = M - 1;
  int br0 = n0 + srow;      if (br0 >= N) br0 = N - 1;
  int br1 = n0 + srow + 64; if (br1 >= N) br1 = N - 1;
  const size_t aof0 = (size_t)ar0 * lda + (sg << 3);
  const size_t aof1 = (size_t)ar1 * lda + (sg << 3);
  const size_t bof0 = (size_t)br0 * ldb + (sg << 3);
  const size_t bof1 = (size_t)br1 * ldb + (sg << 3);
  const int l0 = wid << 9;
  const int l1 = 2048 + (wid << 9);

  fx4 zf = {0.f, 0.f, 0.f, 0.f};
  fx4 acc[4][4];
#pragma unroll
  for (int a = 0; a < 4; ++a)
#pragma unroll
    for (int b = 0; b < 4; ++b) acc[a][b] = zf;

  const int nk = (K + 31) >> 5;
  for (int ki = 0; ki < nk; ++ki) {
    const int k0 = ki << 5;
    if (ki) __syncthreads();  // previous tile's frag reads done

    gload16(Ahi + aof0 + k0, &As[0][l0]);
    gload16(Ahi + aof1 + k0, &As[0][l1]);
    gload16(Alo + aof0 + k0, &As[1][l0]);
    gload16(Alo + aof1 + k0, &As[1][l1]);
    gload16(Bhi + bof0 + k0, &Bs[0][l0]);
    gload16(Bhi + bof1 + k0, &Bs[0][l1]);
    gload16(Blo + bof0 + k0, &Bs[1][l0]);
    gload16(Blo + bof1 + k0, &Bs[1][l1]);
    __syncthreads();  // drains vmcnt (gload_lds)

    short8 ah[4], al[4], bh[4], bl[4];
#pragma unroll
    for (int t = 0; t < 4; ++t) {
      const int rA = wm + t * 16 + l15;
      const int oa = rA * 32 + (((quad ^ rA ^ (rA >> 2)) & 3) << 3);
      ah[t] = *(const short8*)&As[0][oa];
      al[t] = *(const short8*)&As[1][oa];
      const int rB = wn + t * 16 + l15;
      const int ob = rB * 32 + (((quad ^ rB ^ (rB >> 2)) & 3) << 3);
      bh[t] = *(const short8*)&Bs[0][ob];
      bl[t] = *(const short8*)&Bs[1][ob];
    }
#pragma unroll
    for (int a = 0; a < 4; ++a)
#pragma unroll
      for (int b = 0; b < 4; ++b) {
        acc[a][b] = __builtin_amdgcn_mfma_f32_16x16x32_bf16(ah[a], bh[b], acc[a][b], 0, 0, 0);
        acc[a][b] = __builtin_amdgcn_mfma_f32_16x16x32_bf16(ah[a], bl[b], acc[a][b], 0, 0, 0);
        acc[a][b] = __builtin_amdgcn_mfma_f32_16x16x32_bf16(al[a], bh[b], acc[a][b], 0, 0, 0);
      }
  }

#pragma unroll
  for (int a = 0; a < 4; ++a)
#pragma unroll
    for (int b = 0; b < 4; ++b) {
      const int gn = n0 + wn + b * 16 + l15;
      if (gn >= ldc) continue;
      const bool live = gn < N;
      const float bv = (OUTMODE == 1 && live) ? bias[gn] : 0.f;
#pragma unroll
      for (int r = 0; r < 4; ++r) {
        const int gm = m0 + wm + a * 16 + quad * 4 + r;
        if (gm >= M) continue;
        float v = live ? acc[a][b][r] : 0.f;
        if (OUTMODE == 1) {
          v = live ? fmaxf(v + bv, 0.f) : 0.f;
          const u16 hb = bf16_rn(v);
          Chi[(size_t)gm * ldc + gn] = hb;
          Clo[(size_t)gm * ldc + gn] = bf16_rn(v - bf16_f(hb));
        } else {
          Cf[(size_t)gm * ldc + gn] = v;
        }
      }
    }
}

// ============== dbuf GEMM (R7/R11 body) — long-K path (nk>=40) =============
template <int OUTMODE>
__global__ __launch_bounds__(256, 2) void gemm_db(
    const u16* __restrict__ Ahi, const u16* __restrict__ Alo,
    const u16* __restrict__ Bhi, const u16* __restrict__ Blo,
    const float* __restrict__ bias,
    float* __restrict__ Cf, u16* __restrict__ Chi, u16* __restrict__ Clo,
    int M, int N, int K, int lda, int ldb, int ldc, int tm, int tn) {
  __shared__ __align__(16) u16 As[2][2][128 * 32];  // [buf][hi/lo]
  __shared__ __align__(16) u16 Bs[2][2][128 * 32];

  int mt, nt;
  map_tile(blockIdx.x, tm, tn, tm * tn, mt, nt);
  const int m0 = mt * 128;
  const int n0 = nt * 128;

  const int tid = threadIdx.x;
  const int lane = tid & 63;
  const int wid = tid >> 6;
  const int wm = (wid >> 1) * 64;
  const int wn = (wid & 1) * 64;
  const int quad = lane >> 4;
  const int l15 = lane & 15;

  const int srow = tid >> 2;
  const int sg = ((tid & 3) ^ srow ^ (srow >> 2)) & 3;
  int ar0 = m0 + srow;      if (ar0 >= M) ar0 = M - 1;
  int ar1 = m0 + srow + 64; if (ar1 >= M) ar1 = M - 1;
  int br0 = n0 + srow;      if (br0 >= N) br0 = N - 1;
  int br1 = n0 + srow + 64; if (br1 >= N) br1 = N - 1;
  const size_t aof0 = (size_t)ar0 * lda + (sg << 3);
  const size_t aof1 = (size_t)ar1 * lda + (sg << 3);
  const size_t bof0 = (size_t)br0 * ldb + (sg << 3);
  const size_t bof1 = (size_t)br1 * ldb + (sg << 3);
  const int l0 = wid << 9;
  const int l1 = 2048 + (wid << 9);

  fx4 zf = {0.f, 0.f, 0.f, 0.f};
  fx4 acc[4][4];
#pragma unroll
  for (int a = 0; a < 4; ++a)
#pragma unroll
    for (int b = 0; b < 4; ++b) acc[a][b] = zf;

  const int nk = (K + 31) >> 5;

  // ---- prologue: stage tile 0 into buf 0 ----
  gload16(Ahi + aof0, &As[0][0][l0]);
  gload16(Ahi + aof1, &As[0][0][l1]);
  gload16(Alo + aof0, &As[0][1][l0]);
  gload16(Alo + aof1, &As[0][1][l1]);
  gload16(Bhi + bof0, &Bs[0][0][l0]);
  gload16(Bhi + bof1, &Bs[0][0][l1]);
  gload16(Blo + bof0, &Bs[0][1][l0]);
  gload16(Blo + bof1, &Bs[0][1][l1]);

  for (int ki = 0; ki < nk; ++ki) {
    const int cur = ki & 1;
    // drains tile-ki loads (issued one full compute phase ago)
    __syncthreads();

    if (ki + 1 < nk) {
      const size_t kn = (size_t)(ki + 1) << 5;
      gload16(Ahi + aof0 + kn, &As[cur ^ 1][0][l0]);
      gload16(Ahi + aof1 + kn, &As[cur ^ 1][0][l1]);
      gload16(Alo + aof0 + kn, &As[cur ^ 1][1][l0]);
      gload16(Alo + aof1 + kn, &As[cur ^ 1][1][l1]);
      gload16(Bhi + bof0 + kn, &Bs[cur ^ 1][0][l0]);
      gload16(Bhi + bof1 + kn, &Bs[cur ^ 1][0][l1]);
      gload16(Blo + bof0 + kn, &Bs[cur ^ 1][1][l0]);
      gload16(Blo + bof1 + kn, &Bs[cur ^ 1][1][l1]);
    }

    short8 ah[4], al[4], bh[4], bl[4];
#pragma unroll
    for (int t = 0; t < 4; ++t) {
      const int rA = wm + t * 16 + l15;
      const int oa = rA * 32 + (((quad ^ rA ^ (rA >> 2)) & 3) << 3);
      ah[t] = *(const short8*)&As[cur][0][oa];
      al[t] = *(const short8*)&As[cur][1][oa];
      const int rB = wn + t * 16 + l15;
      const int ob = rB * 32 + (((quad ^ rB ^ (rB >> 2)) & 3) << 3);
      bh[t] = *(const short8*)&Bs[cur][0][ob];
      bl[t] = *(const short8*)&Bs[cur][1][ob];
    }
#pragma unroll
    for (int a = 0; a < 4; ++a)
#pragma unroll
      for (int b = 0; b < 4; ++b) {
        acc[a][b] = __builtin_amdgcn_mfma_f32_16x16x32_bf16(ah[a], bh[b], acc[a][b], 0, 0, 0);
        acc[a][b] = __builtin_amdgcn_mfma_f32_16x16x32_bf16(ah[a], bl[b], acc[a][b], 0, 0, 0);
        acc[a][b] = __builtin_amdgcn_mfma_f32_16x16x32_bf16(al[a], bh[b], acc[a][b], 0, 0, 0);
      }
  }

#pragma unroll
  for (int a = 0; a < 4; ++a)
#pragma unroll
    for (int b = 0; b < 4; ++b) {
      const int gn = n0 + wn + b * 16 + l15;
      if (gn >= ldc) continue;
      const bool live = gn < N;
      const float bv = (OUTMODE == 1 && live) ? bias[gn] : 0.f;
#pragma unroll
      for (int r = 0; r < 4; ++r) {
        const int gm = m0 + wm + a * 16 + quad * 4 + r;
        if (gm >= M) continue;
        float v = live ? acc[a][b][r] : 0.f;
        if (OUTMODE == 1) {
          v = live ? fmaxf(v + bv, 0.f) : 0.f;
          const u16 hb = bf16_rn(v);
          Chi[(size_t)gm * ldc + gn] = hb;
          Clo[(size_t)gm * ldc + gn] = bf16_rn(v - bf16_f(hb));
        } else {
          Cf[(size_t)gm * ldc + gn] = v;
        }
      }
    }
}

// ================= R6-path GEMM for fp32-A (layer-0 G1 only) ===============
__global__ __launch_bounds__(256, 2) void gemm_splita(
    const float* __restrict__ Af,
    const u16* __restrict__ Bhi, const u16* __restrict__ Blo,
    const float* __restrict__ bias,
    u16* __restrict__ Chi, u16* __restrict__ Clo,
    int M, int N, int K, int lda, int ldb, int ldc, int tm, int tn) {
  __shared__ __align__(16) u16 As[2][128 * 32];
  __shared__ __align__(16) u16 Bs[2][128 * 32];

  int mt, nt;
  map_tile(blockIdx.x, tm, tn, tm * tn, mt, nt);
  const int m0 = mt * 128;
  const int n0 = nt * 128;

  const int tid = threadIdx.x;
  const int lane = tid & 63;
  const int wid = tid >> 6;
  const int wm = (wid >> 1) * 64;
  const int wn = (wid & 1) * 64;
  const int quad = lane >> 4;
  const int l15 = lane & 15;

  const int srow = tid >> 2;
  const int sg = ((tid & 3) ^ srow ^ (srow >> 2)) & 3;
  int ar0 = m0 + srow;      if (ar0 >= M) ar0 = M - 1;
  int ar1 = m0 + srow + 64; if (ar1 >= M) ar1 = M - 1;
  int br0 = n0 + srow;      if (br0 >= N) br0 = N - 1;
  int br1 = n0 + srow + 64; if (br1 >= N) br1 = N - 1;
  const size_t aof0 = (size_t)ar0 * lda + (sg << 3);
  const size_t aof1 = (size_t)ar1 * lda + (sg << 3);
  const size_t bof0 = (size_t)br0 * ldb + (sg << 3);
  const size_t bof1 = (size_t)br1 * ldb + (sg << 3);
  const int l0 = wid << 9;
  const int l1 = 2048 + (wid << 9);
  const int wls = srow * 32 + ((tid & 3) << 3);

  fx4 zf = {0.f, 0.f, 0.f, 0.f};
  fx4 acc[4][4];
#pragma unroll
  for (int a = 0; a < 4; ++a)
#pragma unroll
    for (int b = 0; b < 4; ++b) acc[a][b] = zf;

  const int nk = (K + 31) >> 5;
  for (int ki = 0; ki < nk; ++ki) {
    const int k0 = ki << 5;
    u16x8 va_h[2], va_l[2];
#pragma unroll
    for (int it = 0; it < 2; ++it) {
      const float* pp = Af + (it ? aof1 : aof0) + k0;
      const fx4 f0 = *(const fx4*)pp;
      const fx4 f1 = *(const fx4*)(pp + 4);
      u16x8 h, l;
#pragma unroll
      for (int j = 0; j < 4; ++j) {
        const u16 hb = bf16_rn(f0[j]);
        h[j] = hb;
        l[j] = bf16_rn(f0[j] - bf16_f(hb));
      }
#pragma unroll
      for (int j = 0; j < 4; ++j) {
        const u16 hb = bf16_rn(f1[j]);
        h[4 + j] = hb;
        l[4 + j] = bf16_rn(f1[j] - bf16_f(hb));
      }
      va_h[it] = h;
      va_l[it] = l;
    }

    if (ki) __syncthreads();

    gload16(Bhi + bof0 + k0, &Bs[0][l0]);
    gload16(Bhi + bof1 + k0, &Bs[0][l1]);
    gload16(Blo + bof0 + k0, &Bs[1][l0]);
    gload16(Blo + bof1 + k0, &Bs[1][l1]);
    *(u16x8*)&As[0][wls] = va_h[0];
    *(u16x8*)&As[0][wls + 2048] = va_h[1];
    *(u16x8*)&As[1][wls] = va_l[0];
    *(u16x8*)&As[1][wls + 2048] = va_l[1];
    __syncthreads();

    short8 ah[4], al[4], bh[4], bl[4];
#pragma unroll
    for (int t = 0; t < 4; ++t) {
      const int rA = wm + t * 16 + l15;
      const int oa = rA * 32 + (((quad ^ rA ^ (rA >> 2)) & 3) << 3);
      ah[t] = *(const short8*)&As[0][oa];
      al[t] = *(const short8*)&As[1][oa];
      const int rB = wn + t * 16 + l15;
      const int ob = rB * 32 + (((quad ^ rB ^ (rB >> 2)) & 3) << 3);
      bh[t] = *(const short8*)&Bs[0][ob];
      bl[t] = *(const short8*)&Bs[1][ob];
    }
#pragma unroll
    for (int a = 0; a < 4; ++a)
#pragma unroll
      for (int b = 0; b < 4; ++b) {
        acc[a][b] = __builtin_amdgcn_mfma_f32_16x16x32_bf16(ah[a], bh[b], acc[a][b], 0, 0, 0);
        acc[a][b] = __builtin_amdgcn_mfma_f32_16x16x32_bf16(ah[a], bl[b], acc[a][b], 0, 0, 0);
        acc[a][b] = __builtin_amdgcn_mfma_f32_16x16x32_bf16(al[a], bh[b], acc[a][b], 0, 0, 0);
      }
  }

#pragma unroll
  for (int a = 0; a < 4; ++a)
#pragma unroll
    for (int b = 0; b < 4; ++b) {
      const int gn = n0 + wn + b * 16 + l15;
      if (gn >= ldc) continue;
      const bool live = gn < N;
      const float bv = live ? bias[gn] : 0.f;
#pragma unroll
      for (int r = 0; r < 4; ++r) {
        const int gm = m0 + wm + a * 16 + quad * 4 + r;
        if (gm < M) {
          float v = live ? fmaxf(acc[a][b][r] + bv, 0.f) : 0.f;
          const u16 hb = bf16_rn(v);
          Chi[(size_t)gm * ldc + gn] = hb;
          Clo[(size_t)gm * ldc + gn] = bf16_rn(v - bf16_f(hb));
        }
      }
    }
}

// ================= weight prep: transpose + split (batched) ================
struct TSJob { const float* W; u16* Th; u16* Tl; int K; int Kp; int N; int tiles_k; int base; };
struct TSJobs { TSJob j[12]; };

__global__ __launch_bounds__(256) void transpose_split_all(TSJobs jobs, int njobs) {
  const int b = blockIdx.x;
  int ji = 0;
  while (ji + 1 < njobs && jobs.j[ji + 1].base <= b) ++ji;
  const TSJob J = jobs.j[ji];
  const int t = b - J.base;
  const int k0 = (t % J.tiles_k) * 32;
  const int n0 = (t / J.tiles_k) * 32;
  __shared__ float tile[32][33];
  const int tx = threadIdx.x & 31, ty = threadIdx.x >> 5;
#pragma unroll
  for (int i = 0; i < 32; i += 8) {
    const int k = k0 + ty + i, n = n0 + tx;
    tile[ty + i][tx] = (k < J.K && n < J.N) ? J.W[(size_t)k * J.N + n] : 0.f;
  }
  __syncthreads();
#pragma unroll
  for (int i = 0; i < 32; i += 8) {
    const int n = n0 + ty + i, k = k0 + tx;
    if (n < J.N && k < J.Kp) {
      const float f = tile[tx][ty + i];
      const u16 hb = bf16_rn(f);
      J.Th[(size_t)n * J.Kp + k] = hb;
      J.Tl[(size_t)n * J.Kp + k] = bf16_rn(f - bf16_f(hb));
    }
  }
}

// ========================= Graph preprocessing =============================
__global__ void count_deg(const int* __restrict__ dst, int E, int* __restrict__ cnt) {
  int e = blockIdx.x * blockDim.x + threadIdx.x;
  if (e < E) atomicAdd(&cnt[dst[e]], 1);
}

__global__ void compute_dinv(const int* __restrict__ cnt, float* __restrict__ dinv, int N) {
  int i = blockIdx.x * blockDim.x + threadIdx.x;
  if (i < N) dinv[i] = rsqrtf((float)(cnt[i] + 1));
}

__global__ void scan_block(const int* __restrict__ cnt, int* __restrict__ partial,
                           int* __restrict__ blocksum, int N) {
  __shared__ int s[256];
  const int t = threadIdx.x;
  const int i = blockIdx.x * 256 + t;
  int v = (i < N) ? cnt[i] : 0;
  s[t] = v;
  __syncthreads();
  for (int off = 1; off < 256; off <<= 1) {
    int u = (t >= off) ? s[t - off] : 0;
    __syncthreads();
    s[t] += u;
    __syncthreads();
  }
  if (i < N) partial[i] = s[t];
  if (t == 255) blocksum[blockIdx.x] = s[255];
}

__global__ void scan_sums(int* __restrict__ blocksum, int NB) {
  __shared__ int s[256];
  const int t = threadIdx.x;
  int v = (t < NB) ? blocksum[t] : 0;
  s[t] = v;
  __syncthreads();
  for (int off = 1; off < 256; off <<= 1) {
    int u = (t >= off) ? s[t - off] : 0;
    __syncthreads();
    s[t] += u;
    __syncthreads();
  }
  if (t < NB) blocksum[t] = s[t] - v;
}

__global__ void finalize_rowptr(const int* __restrict__ partial, const int* __restrict__ blockoff,
                                int* __restrict__ rowptr, int N) {
  int i = blockIdx.x * 256 + threadIdx.x;
  if (i < N) rowptr[i + 1] = partial[i] + blockoff[blockIdx.x];
  if (i == 0) rowptr[0] = 0;
}

__global__ void fill_csr(const int* __restrict__ src, const int* __restrict__ dst, int E,
                         const int* __restrict__ rowptr, int* __restrict__ cursor,
                         int* __restrict__ colidx) {
  int e = blockIdx.x * blockDim.x + threadIdx.x;
  if (e < E) {
    int d = dst[e];
    int p = atomicAdd(&cursor[d], 1);
    colidx[rowptr[d] + p] = src[e];
  }
}

// ================= Message passing + bias + BN + ReLU ======================
__global__ void mp_bn_relu(
    const float* __restrict__ H, const int* __restrict__ rowptr,
    const int* __restrict__ colidx, const float* __restrict__ dinv,
    const float* __restrict__ gb, const float* __restrict__ gamma,
    const float* __restrict__ beta, const float* __restrict__ mean,
    const float* __restrict__ var,
    u16* __restrict__ Xh, u16* __restrict__ Xl, int N, int F, int Fp) {
  const int nch = Fp >> 2;
  const int idx = blockIdx.x * blockDim.x + threadIdx.x;
  if (idx >= N * nch) return;
  const int i = idx / nch;
  const int c = idx - i * nch;
  const size_t rowi = (size_t)i * Fp + (c << 2);
  if ((c << 2) >= F) {
    const u16x4 z = {0, 0, 0, 0};
    *(u16x4*)(Xh + rowi) = z;
    *(u16x4*)(Xl + rowi) = z;
    return;
  }
  const float di = dinv[i];
  fx4 acc = (di * di) * *(const fx4*)(H + rowi);
  const int e0 = rowptr[i], e1 = rowptr[i + 1];
  int e = e0;
  for (; e + 4 <= e1; e += 4) {
    const int s0 = colidx[e + 0], s1 = colidx[e + 1];
    const int s2 = colidx[e + 2], s3 = colidx[e + 3];
    const float w0 = di * dinv[s0], w1 = di * dinv[s1];
    const float w2 = di * dinv[s2], w3 = di * dinv[s3];
    const fx4 v0 = *(const fx4*)(H + (size_t)s0 * Fp + (c << 2));
    const fx4 v1 = *(const fx4*)(H + (size_t)s1 * Fp + (c << 2));
    const fx4 v2 = *(const fx4*)(H + (size_t)s2 * Fp + (c << 2));
    const fx4 v3 = *(const fx4*)(H + (size_t)s3 * Fp + (c << 2));
    acc += w0 * v0;
    acc += w1 * v1;
    acc += w2 * v2;
    acc += w3 * v3;
  }
  for (; e < e1; ++e) {
    const int s = colidx[e];
    acc += (di * dinv[s]) * *(const fx4*)(H + (size_t)s * Fp + (c << 2));
  }
  u16x4 oh, ol;
#pragma unroll
  for (int j = 0; j < 4; ++j) {
    const int col = (c << 2) + j;
    float v = (acc[j] + gb[col] - mean[col]) * rsqrtf(var[col] + EPS_BN) * gamma[col] + beta[col];
    v = fmaxf(v, 0.f);
    const u16 hb = bf16_rn(v);
    oh[j] = hb;
    ol[j] = bf16_rn(v - bf16_f(hb));
  }
  *(u16x4*)(Xh + rowi) = oh;
  *(u16x4*)(Xl + rowi) = ol;
}

// ========================= global max pool (segments) ======================
__global__ void pool_seg(const u16* __restrict__ Xh, const u16* __restrict__ Xl,
                         const int* __restrict__ batch, float* __restrict__ out,
                         int N, int F, int ldx) {
  const int g = blockIdx.x;
  int lo = 0, hi = N;
  while (lo < hi) { int m = (lo + hi) >> 1; if (batch[m] < g) lo = m + 1; else hi = m; }
  const int s0 = lo;
  hi = N;
  while (lo < hi) { int m = (lo + hi) >> 1; if (batch[m] <= g) lo = m + 1; else hi = m; }
  const int s1 = lo;
  const int c = threadIdx.x;
  if (c * 4 >= F) return;
  fx4 mx = {-INFINITY, -INFINITY, -INFINITY, -INFINITY};
  for (int i = s0; i < s1; ++i) {
    const size_t off = (size_t)i * ldx + (c << 2);
    const u16x4 h = *(const u16x4*)(Xh + off);
    const u16x4 l = *(const u16x4*)(Xl + off);
#pragma unroll
    for (int j = 0; j < 4; ++j) mx[j] = fmaxf(mx[j], bf16_f(h[j]) + bf16_f(l[j]));
  }
  *(fx4*)(out + (size_t)g * F + (c << 2)) = mx;
}

// =========================== launch ========================================
extern "C" void kernel_launch(void* const* d_in, const int* in_sizes, int n_in,
                              void* d_out, int out_size, void* d_ws, size_t ws_size,
                              hipStream_t stream) {
  const float* x = (const float*)d_in[0];
  const int* edges = (const int*)d_in[1];
  const int* batch = (const int*)d_in[2];
  const int E = in_sizes[1] / 2;
  const int Nn = in_sizes[2];

  static const int FDS[4]  = {80, 160, 400, 600};
  static const int FDP[4]  = {96, 160, 416, 608};
  static const int DINS[4] = {3072, 80, 160, 400};
  static const int DINP[4] = {3072, 96, 160, 416};
  const float *wa[4], *ba[4], *wb[4], *bb[4], *gw[4], *gb[4], *gamma[4], *beta[4], *mean[4], *var[4];
  for (int i = 0; i < 4; ++i) {
    const int b = 3 + 10 * i;
    wa[i] = (const float*)d_in[b + 0];
    ba[i] = (const float*)d_in[b + 1];
    wb[i] = (const float*)d_in[b + 2];
    bb[i] = (const float*)d_in[b + 3];
    gw[i] = (const float*)d_in[b + 4];
    gb[i] = (const float*)d_in[b + 5];
    gamma[i] = (const float*)d_in[b + 6];
    beta[i] = (const float*)d_in[b + 7];
    mean[i] = (const float*)d_in[b + 8];
    var[i] = (const float*)d_in[b + 9];
  }

  char* p = (char*)d_ws;
  auto alloc = [&](size_t bytes) {
    char* r = p;
    p += (bytes + 255) & ~(size_t)255;
    return r;
  };
  u16* actA_h = (u16*)alloc((size_t)Nn * 2400 * 2);
  u16* actA_l = (u16*)alloc((size_t)Nn * 2400 * 2);
  u16* actB_h = (u16*)alloc((size_t)Nn * 608 * 2);
  u16* actB_l = (u16*)alloc((size_t)Nn * 608 * 2);
  float* H3 = (float*)actA_h;

  u16 *waT_h[4], *waT_l[4], *wbT_h[4], *wbT_l[4], *gwT_h[4], *gwT_l[4];
  for (int i = 0; i < 4; ++i) {
    const size_t s1 = (size_t)4 * FDS[i] * DINP[i];
    const size_t s2 = (size_t)FDS[i] * 4 * FDS[i];
    const size_t s3 = (size_t)FDS[i] * FDP[i];
    waT_h[i] = (u16*)alloc(s1 * 2);
    waT_l[i] = (u16*)alloc(s1 * 2);
    wbT_h[i] = (u16*)alloc(s2 * 2);
    wbT_l[i] = (u16*)alloc(s2 * 2);
    gwT_h[i] = (u16*)alloc(s3 * 2);
    gwT_l[i] = (u16*)alloc(s3 * 2);
  }

  int* cnt = (int*)alloc((size_t)Nn * sizeof(int));
  int* cursor = (int*)alloc((size_t)Nn * sizeof(int));
  int* partial = (int*)alloc((size_t)Nn * sizeof(int));
  int* blocksum = (int*)alloc(256 * sizeof(int));
  int* rowptr = (int*)alloc((size_t)(Nn + 1) * sizeof(int));
  int* colidx = (int*)alloc((size_t)E * sizeof(int));
  float* dinv = (float*)alloc((size_t)Nn * sizeof(float));

  const int* srcIdx = edges;
  const int* dstIdx = edges + E;

  {
    TSJobs jobs;
    int base = 0, ji = 0;
    auto addjob = [&](const float* W, int K, int Kp, int Ncols, u16* Th, u16* Tl) {
      const int tk = Kp / 32, tn = (Ncols + 31) / 32;
      jobs.j[ji++] = TSJob{W, Th, Tl, K, Kp, Ncols, tk, base};
      base += tk * tn;
    };
    for (int i = 0; i < 4; ++i) {
      addjob(wa[i], DINS[i], DINP[i], 4 * FDS[i], waT_h[i], waT_l[i]);
      addjob(wb[i], 4 * FDS[i], 4 * FDS[i], FDS[i], wbT_h[i], wbT_l[i]);
      addjob(gw[i], FDS[i], FDP[i], FDS[i], gwT_h[i], gwT_l[i]);
    }
    transpose_split_all<<<base, 256, 0, stream>>>(jobs, 12);
  }

  hipMemsetAsync(cnt, 0, (size_t)Nn * sizeof(int), stream);
  hipMemsetAsync(cursor, 0, (size_t)Nn * sizeof(int), stream);

  const int EB = (E + 255) / 256;
  const int NB = (Nn + 255) / 256;
  count_deg<<<EB, 256, 0, stream>>>(dstIdx, E, cnt);
  compute_dinv<<<NB, 256, 0, stream>>>(cnt, dinv, Nn);
  scan_block<<<NB, 256, 0, stream>>>(cnt, partial, blocksum, Nn);
  scan_sums<<<1, 256, 0, stream>>>(blocksum, NB);
  finalize_rowptr<<<NB, 256, 0, stream>>>(partial, blocksum, rowptr, Nn);
  fill_csr<<<EB, 256, 0, stream>>>(srcIdx, dstIdx, E, rowptr, cursor, colidx);

  const int tm = (Nn + 127) / 128;
  for (int i = 0; i < 4; ++i) {
    const int fd = FDS[i], fdp = FDP[i];
    const int hid = 4 * fd;
    const int din = DINS[i], dinp = DINP[i];

    // G1: X @ wa + ba, relu -> H1 (split, ldc = hid)
    {
      const int tn = (hid + 127) / 128;
      if (i == 0) {
        gemm_splita<<<tm * tn, 256, 0, stream>>>(
            x, waT_h[0], waT_l[0], ba[0],
            actA_h, actA_l, Nn, hid, din, din, dinp, hid, tm, tn);
      } else {
        gemm_sb<1><<<tm * tn, 256, 0, stream>>>(
            actB_h, actB_l, waT_h[i], waT_l[i], ba[i],
            nullptr, actA_h, actA_l, Nn, hid, din, dinp, dinp, hid, tm, tn);
      }
    }
    // G2: H1 @ wb + bb, relu -> H2 (split, ldc = fdp, zero pads)
    // dbuf body for long-K (nk>=40): L2-G2 (K=1600), L3-G2 (K=2400)
    {
      const int tn = (fd + 127) / 128;
      if (hid >= 1280) {
        gemm_db<1><<<tm * tn, 256, 0, stream>>>(
            actA_h, actA_l, wbT_h[i], wbT_l[i], bb[i],
            nullptr, actB_h, actB_l, Nn, fd, hid, hid, hid, fdp, tm, tn);
      } else {
        gemm_sb<1><<<tm * tn, 256, 0, stream>>>(
            actA_h, actA_l, wbT_h[i], wbT_l[i], bb[i],
            nullptr, actB_h, actB_l, Nn, fd, hid, hid, hid, fdp, tm, tn);
      }
    }
    // G3: H2 @ gw -> H3 (fp32, ldc = fdp, zero pads)
    {
      const int tn = (fd + 127) / 128;
      gemm_sb<0><<<tm * tn, 256, 0, stream>>>(
          actB_h, actB_l, gwT_h[i], gwT_l[i], nullptr,
          H3, nullptr, nullptr, Nn, fd, fd, fdp, fdp, fdp, tm, tn);
    }
    // MP + bias + BN + ReLU -> X_next
    {
      const int items = Nn * (fdp >> 2);
      mp_bn_relu<<<(items + 255) / 256, 256, 0, stream>>>(
          H3, rowptr, colidx, dinv, gb[i], gamma[i], beta[i], mean[i], var[i],
          actB_h, actB_l, Nn, fd, fdp);
    }
  }

  pool_seg<<<out_size / 600, 192, 0, stream>>>(actB_h, actB_l, batch, (float*)d_out,
                                               Nn, 600, 608);
}